// Round 4
// baseline (48.480 us; speedup 1.0000x reference)
//
#include <hip/hip_runtime.h>
#include <hip/hip_bf16.h>

// Problem constants
#define L_CNT 128
#define R_CNT 1024
#define T_CNT 16
#define E_CNT 32

// rbf = exp(-((d-mu)/sigma)^2), sigma = -0.3125 -> 1/sigma^2 = 10.24
// exp2 domain: rbf_e(d) = exp2(-(d*SFAC - e*MUS)^2), MUS = SFAC*10/31.
constexpr float SFAC    = 3.8435917f;              // sqrt(10.24 * log2(e))
constexpr float MUS     = SFAC * (10.0f / 31.0f);  // 1.2398683
constexpr float INV_MUS = 1.0f / MUS;
constexpr float FIXSCALE = 2097152.0f;             // 2^21 fixed-point scale
constexpr double INV_FIXSCALE = 1.0 / 2097152.0;

#if defined(__has_builtin)
#  if __has_builtin(__builtin_amdgcn_exp2f)
#    define EXP2(x) __builtin_amdgcn_exp2f(x)
#  endif
#endif
#ifndef EXP2
#  define EXP2(x) exp2f(x)
#endif

typedef __attribute__((ext_vector_type(8))) short short8_t;
typedef __attribute__((ext_vector_type(4))) float f32x4;

__device__ __forceinline__ short f2bf(float f) {
    __bf16 h = (__bf16)f;
    return __builtin_bit_cast(short, h);
}

// ---------------------------------------------------------------------------
// Kernel A: atn[e][l][r] (bf16) = sum_f lig[l,e,f]*rec[r,e,f] via bf16 MFMA.
// Grid (32 e, 2 lt, 8 rt), block 256 = 4 waves. Tile 64l x 128r, K=64.
// Epilogue: fragments -> LDS (XOR-swizzled, conflict-free) -> coalesced
// dwordx4 global stores (replaces 32 scalar u16 stores/thread).
// Block (0,0,0) also zeroes the 17 u64 finals (16 fixed-point sums + counter)
// so the energy kernel's last-block pattern is replay-deterministic.
// ---------------------------------------------------------------------------
#define PADK 72
#define CPAD 136   // Cs row stride in shorts (272 B = 17*16 -> 16B-aligned rows)

__global__ __launch_bounds__(256) void atn_mfma(const float* __restrict__ lig,
                                                const float* __restrict__ rec,
                                                unsigned short* __restrict__ atn,
                                                unsigned long long* __restrict__ finals) {
    const int e   = blockIdx.x;
    const int l0  = blockIdx.y * 64;
    const int r0  = blockIdx.z * 128;
    const int tid = threadIdx.x;

    if ((blockIdx.x | blockIdx.y | blockIdx.z) == 0 && tid < 17) finals[tid] = 0ULL;

    __shared__ __align__(16) short smem[64 * PADK + 128 * PADK];  // 27648 B
    short* As = smem;                 // 64 x PADK
    short* Bs = smem + 64 * PADK;     // 128 x PADK
    short* Cs = smem;                 // reused: 64 x CPAD = 8704 shorts

    // Stage lig tile: 64 rows x 64 f (cvt fp32->bf16)
#pragma unroll
    for (int i = 0; i < 4; ++i) {
        int idx = i * 256 + tid;
        int row = idx >> 4;
        int f4  = idx & 15;
        float4 v = *(const float4*)(lig + ((size_t)(l0 + row) * 32 + e) * 64 + f4 * 4);
        short4 p;
        p.x = f2bf(v.x); p.y = f2bf(v.y); p.z = f2bf(v.z); p.w = f2bf(v.w);
        *(short4*)(&As[row * PADK + f4 * 4]) = p;
    }
    // Stage rec tile: 128 rows x 64 f
#pragma unroll
    for (int i = 0; i < 8; ++i) {
        int idx = i * 256 + tid;
        int row = idx >> 4;
        int f4  = idx & 15;
        float4 v = *(const float4*)(rec + ((size_t)(r0 + row) * 32 + e) * 64 + f4 * 4);
        short4 p;
        p.x = f2bf(v.x); p.y = f2bf(v.y); p.z = f2bf(v.z); p.w = f2bf(v.w);
        *(short4*)(&Bs[row * PADK + f4 * 4]) = p;
    }
    __syncthreads();

    const int wave = tid >> 6;
    const int lane = tid & 63;
    const int fr   = lane & 15;
    const int kg   = lane >> 4;

    f32x4 acc[8];
#pragma unroll
    for (int n = 0; n < 8; ++n) acc[n] = (f32x4){0.f, 0.f, 0.f, 0.f};

    short8_t a0 = *(short8_t*)(&As[(16 * wave + fr) * PADK + kg * 8]);
    short8_t a1 = *(short8_t*)(&As[(16 * wave + fr) * PADK + 32 + kg * 8]);

#pragma unroll
    for (int n = 0; n < 8; ++n) {
        short8_t b0 = *(short8_t*)(&Bs[(16 * n + fr) * PADK + kg * 8]);
        short8_t b1 = *(short8_t*)(&Bs[(16 * n + fr) * PADK + 32 + kg * 8]);
        acc[n] = __builtin_amdgcn_mfma_f32_16x16x32_bf16(a0, b0, acc[n], 0, 0, 0);
        acc[n] = __builtin_amdgcn_mfma_f32_16x16x32_bf16(a1, b1, acc[n], 0, 0, 0);
    }
    __syncthreads();   // all waves done reading As/Bs before Cs overwrite

    // Fragment -> LDS. C/D layout: col = lane&15, row = (lane>>4)*4 + j.
    // XOR-swizzle col-group by ((row>>2)&3)<<4 shorts: the 4 row-groups of a
    // wave land on disjoint bank octets -> conflict-free b16 writes.
    const int orow_l = 16 * wave + (lane >> 4) * 4;
    const int sw_w   = ((orow_l >> 2) & 3) << 4;   // j<4 doesn't change row>>2
#pragma unroll
    for (int n = 0; n < 8; ++n) {
#pragma unroll
        for (int j = 0; j < 4; ++j) {
            Cs[(orow_l + j) * CPAD + ((16 * n + fr) ^ sw_w)] = f2bf(acc[n][j]);
        }
    }
    __syncthreads();

    // Read back 8 contiguous logical cols (swizzle self-inverts) and store
    // coalesced 16B/lane: lanes 0-15 cover one row's 256 B contiguously.
#pragma unroll
    for (int it2 = 0; it2 < 4; ++it2) {
        int idx = it2 * 256 + tid;       // 0..1023
        int row = idx >> 4;              // 0..63
        int c8  = idx & 15;
        int sw  = ((row >> 2) & 3) << 4;
        short8_t v = *(short8_t*)(&Cs[row * CPAD + ((c8 * 8) ^ sw)]);
        *(short8_t*)(&atn[((size_t)e * 128 + l0 + row) * 1024 + r0 + c8 * 8]) = v;
    }
}

// ---------------------------------------------------------------------------
// Kernel B: per (l,r) pair, acc[t] += atn[e,l,r]*exp2(-(d*SFAC - e*MUS)^2)
// over the 5-wide e-window around e0 = round(d*SFAC/MUS) (dropped terms
// <= 1.3e-3 each; signed-random sum error ~5 << threshold 132).
// Grid 512 (128 l x 4 r-chunks of 256), block 256, 1 pair/thread.
// Finish: per-block partial -> int64 fixed-point atomicAdd (exact, order-
// independent => deterministic); last block (counter) converts -> out[16].
// ---------------------------------------------------------------------------
__global__ __launch_bounds__(256) void energy_kernel(const unsigned short* __restrict__ atn,
                                                     const float* __restrict__ ligc,
                                                     const float* __restrict__ recc,
                                                     unsigned long long* __restrict__ finals,
                                                     float* __restrict__ out) {
    __shared__ unsigned int atn_sd[E_CNT * 128];          // [32][256] bf16 = 16 KB
    const unsigned short* atn_su = (const unsigned short*)atn_sd;
    __shared__ float red[4][T_CNT];
    __shared__ unsigned int lastflag;

    const int tid   = threadIdx.x;
    const int l     = blockIdx.x >> 2;
    const int rbase = (blockIdx.x & 3) * 256;
    const int r     = rbase + tid;

    // T14 split: issue atn dword loads early (32 e x 128 dwords)
    const unsigned int* atn_d = (const unsigned int*)atn;
    unsigned int stage[16];
#pragma unroll
    for (int it = 0; it < 16; ++it) {
        int idx = it * 256 + tid;
        int ee  = idx >> 7;
        int rh  = idx & 127;
        stage[it] = atn_d[(size_t)ee * 65536 + (size_t)l * 512 + (rbase >> 1) + rh];
    }

    // distances (overlap the loads)
    const float rx = recc[r * 3 + 0];
    const float ry = recc[r * 3 + 1];
    const float rz = recc[r * 3 + 2];

    float d[T_CNT];
#pragma unroll
    for (int t = 0; t < T_CNT; ++t) {
        float dx = ligc[((size_t)t * 128 + l) * 3 + 0] - rx;
        float dy = ligc[((size_t)t * 128 + l) * 3 + 1] - ry;
        float dz = ligc[((size_t)t * 128 + l) * 3 + 2] - rz;
        d[t] = sqrtf(dx * dx + dy * dy + dz * dz);
    }

#pragma unroll
    for (int it = 0; it < 16; ++it) atn_sd[it * 256 + tid] = stage[it];
    __syncthreads();

    float acc[T_CNT];
#pragma unroll
    for (int t = 0; t < T_CNT; ++t) acc[t] = 0.0f;

#pragma unroll
    for (int t = 0; t < T_CNT; ++t) {
        const float u = d[t] * SFAC;
        float e0f = rintf(u * INV_MUS);
        e0f = fminf(fmaxf(e0f, 2.0f), 29.0f);   // window [e0-2, e0+2] in [0,31]
        const int   em2 = (int)e0f - 2;
        const float um  = fmaf(e0f, -MUS, u);
#pragma unroll
        for (int k = 0; k < 5; ++k) {
            const float w  = um - (float)(k - 2) * MUS;
            const float ae = __uint_as_float((unsigned)atn_su[(em2 + k) * 256 + tid] << 16);
            acc[t] = fmaf(ae, EXP2(-(w * w)), acc[t]);
        }
    }

    // Block reduction: shuffle within wave, then LDS across 4 waves.
    const int lane = tid & 63;
    const int wid  = tid >> 6;
#pragma unroll
    for (int t = 0; t < T_CNT; ++t) {
#pragma unroll
        for (int m = 32; m >= 1; m >>= 1) acc[t] += __shfl_xor(acc[t], m, 64);
    }
    if (lane == 0) {
#pragma unroll
        for (int t = 0; t < T_CNT; ++t) red[wid][t] = acc[t];
    }
    __syncthreads();

    // Fixed-point accumulate (exact integer add => order-independent).
    if (tid < T_CNT) {
        float s = red[0][tid] + red[1][tid] + red[2][tid] + red[3][tid];
        long long q = (long long)llrintf(s * FIXSCALE);
        atomicAdd(&finals[tid], (unsigned long long)q);
    }
    __threadfence();            // release: t-sums visible before counter bump
    __syncthreads();
    if (tid == 0) {
        unsigned long long old = atomicAdd(&finals[16], 1ULL);
        lastflag = (old == 511ULL) ? 1u : 0u;
    }
    __syncthreads();
    if (lastflag) {
        __threadfence();        // acquire
        if (tid < T_CNT) {
            unsigned long long v = atomicAdd(&finals[tid], 0ULL);  // coherent read
            out[tid] = (float)((double)(long long)v * INV_FIXSCALE);
        }
    }
}

extern "C" void kernel_launch(void* const* d_in, const int* in_sizes, int n_in,
                              void* d_out, int out_size, void* d_ws, size_t ws_size,
                              hipStream_t stream) {
    const float* lig  = (const float*)d_in[0];   // [128,32,64]
    const float* rec  = (const float*)d_in[1];   // [1024,32,64]
    const float* ligc = (const float*)d_in[2];   // [16,128,3]
    const float* recc = (const float*)d_in[3];   // [1024,3]
    float* out = (float*)d_out;                  // [16]

    unsigned short* atn = (unsigned short*)d_ws;                 // 8 MB bf16
    unsigned long long* finals =
        (unsigned long long*)((char*)d_ws + (size_t)E_CNT * L_CNT * R_CNT * 2);

    atn_mfma<<<dim3(E_CNT, 2, 8), 256, 0, stream>>>(lig, rec, atn, finals);
    energy_kernel<<<512, 256, 0, stream>>>(atn, ligc, recc, finals, out);
}

// Round 6
// 27.384 us; speedup vs baseline: 1.7704x; 1.7704x over previous
//
#include <hip/hip_runtime.h>
#include <hip/hip_bf16.h>

// Problem constants
#define L_CNT 128
#define R_CNT 1024
#define T_CNT 16
#define E_CNT 32

// rbf = exp(-((d-mu)/sigma)^2), sigma = -0.3125 -> 1/sigma^2 = 10.24
// exp2 domain: rbf_e(d) = exp2(-(d*SFAC - e*MUS)^2), MUS = SFAC*10/31.
constexpr float SFAC    = 3.8435917f;              // sqrt(10.24 * log2(e))
constexpr float MUS     = SFAC * (10.0f / 31.0f);  // 1.2398683
constexpr float INV_MUS = 1.0f / MUS;

#if defined(__has_builtin)
#  if __has_builtin(__builtin_amdgcn_exp2f)
#    define EXP2(x) __builtin_amdgcn_exp2f(x)
#  endif
#endif
#ifndef EXP2
#  define EXP2(x) exp2f(x)
#endif

typedef __attribute__((ext_vector_type(8))) short short8_t;
typedef __attribute__((ext_vector_type(4))) float f32x4;

__device__ __forceinline__ short f2bf(float f) {
    __bf16 h = (__bf16)f;
    return __builtin_bit_cast(short, h);
}

// ---------------------------------------------------------------------------
// Kernel A: atn[e][l][r] (bf16) = sum_f lig[l,e,f]*rec[r,e,f] via bf16 MFMA.
// Grid (32 e, 2 lt, 8 rt), block 256 = 4 waves. Tile 64l x 128r, K=64.
// Epilogue: fragments -> LDS (XOR-swizzled, conflict-free) -> coalesced
// dwordx4 global stores.
// ---------------------------------------------------------------------------
#define PADK 72
#define CPAD 136   // Cs row stride in shorts (272 B = 17*16 -> 16B-aligned rows)

__global__ __launch_bounds__(256) void atn_mfma(const float* __restrict__ lig,
                                                const float* __restrict__ rec,
                                                unsigned short* __restrict__ atn) {
    const int e   = blockIdx.x;
    const int l0  = blockIdx.y * 64;
    const int r0  = blockIdx.z * 128;
    const int tid = threadIdx.x;

    __shared__ __align__(16) short smem[64 * PADK + 128 * PADK];  // 27648 B
    short* As = smem;                 // 64 x PADK
    short* Bs = smem + 64 * PADK;     // 128 x PADK
    short* Cs = smem;                 // reused: 64 x CPAD shorts

    // Stage lig tile: 64 rows x 64 f (cvt fp32->bf16)
#pragma unroll
    for (int i = 0; i < 4; ++i) {
        int idx = i * 256 + tid;
        int row = idx >> 4;
        int f4  = idx & 15;
        float4 v = *(const float4*)(lig + ((size_t)(l0 + row) * 32 + e) * 64 + f4 * 4);
        short4 p;
        p.x = f2bf(v.x); p.y = f2bf(v.y); p.z = f2bf(v.z); p.w = f2bf(v.w);
        *(short4*)(&As[row * PADK + f4 * 4]) = p;
    }
    // Stage rec tile: 128 rows x 64 f
#pragma unroll
    for (int i = 0; i < 8; ++i) {
        int idx = i * 256 + tid;
        int row = idx >> 4;
        int f4  = idx & 15;
        float4 v = *(const float4*)(rec + ((size_t)(r0 + row) * 32 + e) * 64 + f4 * 4);
        short4 p;
        p.x = f2bf(v.x); p.y = f2bf(v.y); p.z = f2bf(v.z); p.w = f2bf(v.w);
        *(short4*)(&Bs[row * PADK + f4 * 4]) = p;
    }
    __syncthreads();

    const int wave = tid >> 6;
    const int lane = tid & 63;
    const int fr   = lane & 15;
    const int kg   = lane >> 4;

    f32x4 acc[8];
#pragma unroll
    for (int n = 0; n < 8; ++n) acc[n] = (f32x4){0.f, 0.f, 0.f, 0.f};

    short8_t a0 = *(short8_t*)(&As[(16 * wave + fr) * PADK + kg * 8]);
    short8_t a1 = *(short8_t*)(&As[(16 * wave + fr) * PADK + 32 + kg * 8]);

#pragma unroll
    for (int n = 0; n < 8; ++n) {
        short8_t b0 = *(short8_t*)(&Bs[(16 * n + fr) * PADK + kg * 8]);
        short8_t b1 = *(short8_t*)(&Bs[(16 * n + fr) * PADK + 32 + kg * 8]);
        acc[n] = __builtin_amdgcn_mfma_f32_16x16x32_bf16(a0, b0, acc[n], 0, 0, 0);
        acc[n] = __builtin_amdgcn_mfma_f32_16x16x32_bf16(a1, b1, acc[n], 0, 0, 0);
    }
    __syncthreads();   // all waves done reading As/Bs before Cs overwrite

    // Fragment -> LDS. C/D layout: col = lane&15, row = (lane>>4)*4 + j.
    // XOR-swizzle col-group by ((row>>2)&3)<<4 shorts: conflict-free b16 writes.
    const int orow_l = 16 * wave + (lane >> 4) * 4;
    const int sw_w   = ((orow_l >> 2) & 3) << 4;   // j<4 doesn't change row>>2
#pragma unroll
    for (int n = 0; n < 8; ++n) {
#pragma unroll
        for (int j = 0; j < 4; ++j) {
            Cs[(orow_l + j) * CPAD + ((16 * n + fr) ^ sw_w)] = f2bf(acc[n][j]);
        }
    }
    __syncthreads();

    // Read back (swizzle self-inverts) and store coalesced 16B/lane.
#pragma unroll
    for (int it2 = 0; it2 < 4; ++it2) {
        int idx = it2 * 256 + tid;       // 0..1023
        int row = idx >> 4;              // 0..63
        int c8  = idx & 15;
        int sw  = ((row >> 2) & 3) << 4;
        short8_t v = *(short8_t*)(&Cs[row * CPAD + ((c8 * 8) ^ sw)]);
        *(short8_t*)(&atn[((size_t)e * 128 + l0 + row) * 1024 + r0 + c8 * 8]) = v;
    }
}

// ---------------------------------------------------------------------------
// Kernel B: per (l,r) pair, acc[t] += atn[e,l,r]*exp2(-(d*SFAC - e*MUS)^2)
// over the 5-wide e-window around e0 = round(d*SFAC/MUS) (dropped terms
// <= 1.3e-3 each; signed-random sum error ~5 << threshold 132).
// Grid 512 (128 l x 4 r-chunks of 256), block 256, 1 pair/thread.
// Ends with plain-store per-block partials (cheap; NO device-scope fences or
// same-line atomics -- round 4 showed those cost ~35 us of serialization).
// ---------------------------------------------------------------------------
__global__ __launch_bounds__(256) void energy_kernel(const unsigned short* __restrict__ atn,
                                                     const float* __restrict__ ligc,
                                                     const float* __restrict__ recc,
                                                     float* __restrict__ partials) {
    __shared__ unsigned int atn_sd[E_CNT * 128];          // [32][256] bf16 = 16 KB
    const unsigned short* atn_su = (const unsigned short*)atn_sd;
    __shared__ float red[4][T_CNT];

    const int tid   = threadIdx.x;
    const int l     = blockIdx.x >> 2;
    const int rbase = (blockIdx.x & 3) * 256;
    const int r     = rbase + tid;

    // T14 split: issue atn dword loads early (32 e x 128 dwords)
    const unsigned int* atn_d = (const unsigned int*)atn;
    unsigned int stage[16];
#pragma unroll
    for (int it = 0; it < 16; ++it) {
        int idx = it * 256 + tid;
        int ee  = idx >> 7;
        int rh  = idx & 127;
        stage[it] = atn_d[(size_t)ee * 65536 + (size_t)l * 512 + (rbase >> 1) + rh];
    }

    // distances (overlap the loads)
    const float rx = recc[r * 3 + 0];
    const float ry = recc[r * 3 + 1];
    const float rz = recc[r * 3 + 2];

    float d[T_CNT];
#pragma unroll
    for (int t = 0; t < T_CNT; ++t) {
        float dx = ligc[((size_t)t * 128 + l) * 3 + 0] - rx;
        float dy = ligc[((size_t)t * 128 + l) * 3 + 1] - ry;
        float dz = ligc[((size_t)t * 128 + l) * 3 + 2] - rz;
        d[t] = sqrtf(dx * dx + dy * dy + dz * dz);
    }

#pragma unroll
    for (int it = 0; it < 16; ++it) atn_sd[it * 256 + tid] = stage[it];
    __syncthreads();

    float acc[T_CNT];
#pragma unroll
    for (int t = 0; t < T_CNT; ++t) acc[t] = 0.0f;

#pragma unroll
    for (int t = 0; t < T_CNT; ++t) {
        const float u = d[t] * SFAC;
        float e0f = rintf(u * INV_MUS);
        e0f = fminf(fmaxf(e0f, 2.0f), 29.0f);   // window [e0-2, e0+2] in [0,31]
        const int   em2 = (int)e0f - 2;
        const float um  = fmaf(e0f, -MUS, u);
#pragma unroll
        for (int k = 0; k < 5; ++k) {
            const float w  = um - (float)(k - 2) * MUS;
            const float ae = __uint_as_float((unsigned)atn_su[(em2 + k) * 256 + tid] << 16);
            acc[t] = fmaf(ae, EXP2(-(w * w)), acc[t]);
        }
    }

    // Block reduction: shuffle within wave, then LDS across 4 waves.
    const int lane = tid & 63;
    const int wid  = tid >> 6;
#pragma unroll
    for (int t = 0; t < T_CNT; ++t) {
#pragma unroll
        for (int m = 32; m >= 1; m >>= 1) acc[t] += __shfl_xor(acc[t], m, 64);
    }
    if (lane == 0) {
#pragma unroll
        for (int t = 0; t < T_CNT; ++t) red[wid][t] = acc[t];
    }
    __syncthreads();
    if (tid < T_CNT) {
        float s = red[0][tid] + red[1][tid] + red[2][tid] + red[3][tid];
        partials[(size_t)blockIdx.x * T_CNT + tid] = s;
    }
}

// ---------------------------------------------------------------------------
// Kernel C: deterministic final reduce of 512 x 16 partials -> out[16]
// ---------------------------------------------------------------------------
__global__ __launch_bounds__(256) void final_reduce(const float* __restrict__ partials,
                                                    float* __restrict__ out) {
    __shared__ float red[16][17];
    const int t = threadIdx.x & 15;
    const int g = threadIdx.x >> 4;
    float s = 0.0f;
    for (int b = g; b < 512; b += 16) s += partials[(size_t)b * 16 + t];
    red[g][t] = s;
    __syncthreads();
    if (threadIdx.x < 16) {
        float v = 0.0f;
#pragma unroll
        for (int g2 = 0; g2 < 16; ++g2) v += red[g2][threadIdx.x];
        out[threadIdx.x] = v;
    }
}

extern "C" void kernel_launch(void* const* d_in, const int* in_sizes, int n_in,
                              void* d_out, int out_size, void* d_ws, size_t ws_size,
                              hipStream_t stream) {
    const float* lig  = (const float*)d_in[0];   // [128,32,64]
    const float* rec  = (const float*)d_in[1];   // [1024,32,64]
    const float* ligc = (const float*)d_in[2];   // [16,128,3]
    const float* recc = (const float*)d_in[3];   // [1024,3]
    float* out = (float*)d_out;                  // [16]

    unsigned short* atn = (unsigned short*)d_ws;                 // 8 MB bf16
    float* partials = (float*)((char*)d_ws + (size_t)E_CNT * L_CNT * R_CNT * 2);

    atn_mfma<<<dim3(E_CNT, 2, 8), 256, 0, stream>>>(lig, rec, atn);
    energy_kernel<<<512, 256, 0, stream>>>(atn, ligc, recc, partials);
    final_reduce<<<1, 256, 0, stream>>>(partials, out);
}

// Round 7
// 26.132 us; speedup vs baseline: 1.8552x; 1.0479x over previous
//
#include <hip/hip_runtime.h>
#include <hip/hip_bf16.h>

// Problem constants
#define L_CNT 128
#define R_CNT 1024
#define T_CNT 16
#define E_CNT 32

// rbf = exp(-((d-mu)/sigma)^2), sigma = -0.3125 -> 1/sigma^2 = 10.24
// exp2 domain: rbf_e(d) = exp2(-(d*SFAC - e*MUS)^2), MUS = SFAC*10/31.
constexpr float SFAC    = 3.8435917f;              // sqrt(10.24 * log2(e))
constexpr float MUS     = SFAC * (10.0f / 31.0f);  // 1.2398683
constexpr float INV_MUS = 1.0f / MUS;

#if defined(__has_builtin)
#  if __has_builtin(__builtin_amdgcn_exp2f)
#    define EXP2(x) __builtin_amdgcn_exp2f(x)
#  endif
#endif
#ifndef EXP2
#  define EXP2(x) exp2f(x)
#endif

typedef __attribute__((ext_vector_type(8))) short short8_t;
typedef __attribute__((ext_vector_type(4))) float f32x4;

__device__ __forceinline__ short f2bf(float f) {
    __bf16 h = (__bf16)f;
    return __builtin_bit_cast(short, h);
}

#define PADK 72   // bf16 row stride for MFMA staging tiles (144 B)

// Stage one e-group (4 e's) of lig[16 l] and rec[16 r] slices as bf16.
// ligbuf/recbuf: [4][16*PADK] shorts.
__device__ __forceinline__ void stage_group(const float* __restrict__ lig,
                                            const float* __restrict__ rec,
                                            int l0, int r0, int g,
                                            short* __restrict__ ligbuf,
                                            short* __restrict__ recbuf,
                                            int tid) {
#pragma unroll
    for (int i = 0; i < 4; ++i) {              // lig: 4e x 16l x 16 float4
        int idx = i * 256 + tid;
        int eg  = idx >> 8;
        int row = (idx >> 4) & 15;
        int f4  = idx & 15;
        float4 v = *(const float4*)(lig + ((size_t)(l0 + row) * 32 + (4 * g + eg)) * 64 + f4 * 4);
        short4 p;
        p.x = f2bf(v.x); p.y = f2bf(v.y); p.z = f2bf(v.z); p.w = f2bf(v.w);
        *(short4*)(&ligbuf[eg * (16 * PADK) + row * PADK + f4 * 4]) = p;
    }
#pragma unroll
    for (int i = 0; i < 4; ++i) {              // rec: 4e x 16r x 16 float4
        int idx = i * 256 + tid;
        int eg  = idx >> 8;
        int row = (idx >> 4) & 15;
        int f4  = idx & 15;
        float4 v = *(const float4*)(rec + ((size_t)(r0 + row) * 32 + (4 * g + eg)) * 64 + f4 * 4);
        short4 p;
        p.x = f2bf(v.x); p.y = f2bf(v.y); p.z = f2bf(v.z); p.w = f2bf(v.w);
        *(short4*)(&recbuf[eg * (16 * PADK) + row * PADK + f4 * 4]) = p;
    }
}

// ---------------------------------------------------------------------------
// Fused kernel: block = 16 l x 16 r x all 32 e.
// Phase 1: atn tile [32 e][16 l][16 r] (bf16) computed via MFMA into LDS
//          (double-buffered e-group staging; one e per wave per group).
// Phase 2: per (l,r) pair (1 thread each), acc[t] += atn*exp2(-(d*SFAC-e*MUS)^2)
//          over the 5-wide e-window around e0; shuffle reduce -> partials.
// Grid 512 blocks (8 lt x 64 rt), 256 threads = 4 waves, 2 blocks/CU.
// ---------------------------------------------------------------------------
__global__ __launch_bounds__(256) void fused_kernel(const float* __restrict__ lig,
                                                    const float* __restrict__ rec,
                                                    const float* __restrict__ ligc,
                                                    const float* __restrict__ recc,
                                                    float* __restrict__ partials) {
    const int tid = threadIdx.x;
    const int lt  = blockIdx.x >> 6;     // 0..7
    const int rtc = blockIdx.x & 63;     // 0..63
    const int l0  = lt * 16;
    const int r0  = rtc * 16;

    __shared__ short atn_s[E_CNT * 16 * 16];                 // e*256 + l*16 + r, 16 KB
    __shared__ __align__(16) short lig_s[2][4 * 16 * PADK];  // 18432 B
    __shared__ __align__(16) short rec_s[2][4 * 16 * PADK];  // 18432 B
    __shared__ float ligc_s[T_CNT * 16 * 3];                 // [t][l][xyz], 3 KB
    __shared__ float red[4][T_CNT];

    // stage ligc tile: 768 floats
#pragma unroll
    for (int i = 0; i < 3; ++i) {
        int idx = i * 256 + tid;         // t*48 + (l*3+c)
        int t   = idx / 48;
        int rem = idx - t * 48;
        ligc_s[idx] = ligc[(size_t)t * 384 + l0 * 3 + rem];
    }

    const int wave = tid >> 6;
    const int lane = tid & 63;
    const int fr   = lane & 15;
    const int kg   = lane >> 4;

    // ---- Phase 1: GEMM into LDS, 8 e-groups, double-buffered ----
    stage_group(lig, rec, l0, r0, 0, lig_s[0], rec_s[0], tid);
    __syncthreads();

    for (int g = 0; g < 8; ++g) {
        if (g < 7) stage_group(lig, rec, l0, r0, g + 1, lig_s[(g + 1) & 1], rec_s[(g + 1) & 1], tid);

        // compute e = 4g + wave from buffer g&1
        const short* A = &lig_s[g & 1][wave * (16 * PADK)];
        const short* B = &rec_s[g & 1][wave * (16 * PADK)];
        short8_t a0 = *(const short8_t*)(A + fr * PADK + kg * 8);
        short8_t a1 = *(const short8_t*)(A + fr * PADK + 32 + kg * 8);
        short8_t b0 = *(const short8_t*)(B + fr * PADK + kg * 8);
        short8_t b1 = *(const short8_t*)(B + fr * PADK + 32 + kg * 8);
        f32x4 c = (f32x4){0.f, 0.f, 0.f, 0.f};
        c = __builtin_amdgcn_mfma_f32_16x16x32_bf16(a0, b0, c, 0, 0, 0);
        c = __builtin_amdgcn_mfma_f32_16x16x32_bf16(a1, b1, c, 0, 0, 0);

        // C/D layout: col(r) = lane&15, row(l) = (lane>>4)*4 + j
        const int e    = 4 * g + wave;
        const int rowb = (lane >> 4) * 4;
#pragma unroll
        for (int j = 0; j < 4; ++j) {
            atn_s[e * 256 + (rowb + j) * 16 + fr] = f2bf(c[j]);
        }
        __syncthreads();
    }

    // ---- Phase 2: energy. 1 pair/thread: l = tid>>4, r = tid&15 ----
    const int l_loc = tid >> 4;
    const int r_loc = tid & 15;
    const int r_g   = r0 + r_loc;

    const float rx = recc[r_g * 3 + 0];
    const float ry = recc[r_g * 3 + 1];
    const float rz = recc[r_g * 3 + 2];

    float d[T_CNT];
#pragma unroll
    for (int t = 0; t < T_CNT; ++t) {
        float dx = ligc_s[t * 48 + l_loc * 3 + 0] - rx;
        float dy = ligc_s[t * 48 + l_loc * 3 + 1] - ry;
        float dz = ligc_s[t * 48 + l_loc * 3 + 2] - rz;
        d[t] = sqrtf(dx * dx + dy * dy + dz * dz);
    }

    float acc[T_CNT];
#pragma unroll
    for (int t = 0; t < T_CNT; ++t) acc[t] = 0.0f;

    const int pbase = l_loc * 16 + r_loc;
#pragma unroll
    for (int t = 0; t < T_CNT; ++t) {
        const float u = d[t] * SFAC;
        float e0f = rintf(u * INV_MUS);
        e0f = fminf(fmaxf(e0f, 2.0f), 29.0f);   // window [e0-2, e0+2] in [0,31]
        const int   em2 = (int)e0f - 2;
        const float um  = fmaf(e0f, -MUS, u);
#pragma unroll
        for (int k = 0; k < 5; ++k) {
            const float w  = um - (float)(k - 2) * MUS;
            const float ae = __uint_as_float(
                (unsigned)(unsigned short)atn_s[(em2 + k) * 256 + pbase] << 16);
            acc[t] = fmaf(ae, EXP2(-(w * w)), acc[t]);
        }
    }

    // Block reduction: shuffle within wave, then LDS across 4 waves.
#pragma unroll
    for (int t = 0; t < T_CNT; ++t) {
#pragma unroll
        for (int m = 32; m >= 1; m >>= 1) acc[t] += __shfl_xor(acc[t], m, 64);
    }
    if (lane == 0) {
#pragma unroll
        for (int t = 0; t < T_CNT; ++t) red[wave][t] = acc[t];
    }
    __syncthreads();
    if (tid < T_CNT) {
        float s = red[0][tid] + red[1][tid] + red[2][tid] + red[3][tid];
        partials[(size_t)blockIdx.x * T_CNT + tid] = s;
    }
}

// ---------------------------------------------------------------------------
// Deterministic final reduce of 512 x 16 partials -> out[16]
// ---------------------------------------------------------------------------
__global__ __launch_bounds__(256) void final_reduce(const float* __restrict__ partials,
                                                    float* __restrict__ out) {
    __shared__ float red[16][17];
    const int t = threadIdx.x & 15;
    const int g = threadIdx.x >> 4;
    float s = 0.0f;
    for (int b = g; b < 512; b += 16) s += partials[(size_t)b * 16 + t];
    red[g][t] = s;
    __syncthreads();
    if (threadIdx.x < 16) {
        float v = 0.0f;
#pragma unroll
        for (int g2 = 0; g2 < 16; ++g2) v += red[g2][threadIdx.x];
        out[threadIdx.x] = v;
    }
}

extern "C" void kernel_launch(void* const* d_in, const int* in_sizes, int n_in,
                              void* d_out, int out_size, void* d_ws, size_t ws_size,
                              hipStream_t stream) {
    const float* lig  = (const float*)d_in[0];   // [128,32,64]
    const float* rec  = (const float*)d_in[1];   // [1024,32,64]
    const float* ligc = (const float*)d_in[2];   // [16,128,3]
    const float* recc = (const float*)d_in[3];   // [1024,3]
    float* out = (float*)d_out;                  // [16]

    float* partials = (float*)d_ws;              // 512*16 floats

    fused_kernel<<<512, 256, 0, stream>>>(lig, rec, ligc, recc, partials);
    final_reduce<<<1, 256, 0, stream>>>(partials, out);
}

// Round 8
// 25.103 us; speedup vs baseline: 1.9313x; 1.0410x over previous
//
#include <hip/hip_runtime.h>
#include <hip/hip_bf16.h>

// Problem constants
#define L_CNT 128
#define R_CNT 1024
#define T_CNT 16
#define E_CNT 32

// rbf = exp(-((d-mu)/sigma)^2), sigma = -0.3125 -> 1/sigma^2 = 10.24
// exp2 domain: rbf_e(d) = exp2(-(d*SFAC - e*MUS)^2), MUS = SFAC*10/31.
constexpr float SFAC    = 3.8435917f;              // sqrt(10.24 * log2(e))
constexpr float MUS     = SFAC * (10.0f / 31.0f);  // 1.2398683
constexpr float INV_MUS = 1.0f / MUS;

#if defined(__has_builtin)
#  if __has_builtin(__builtin_amdgcn_exp2f)
#    define EXP2(x) __builtin_amdgcn_exp2f(x)
#  endif
#endif
#ifndef EXP2
#  define EXP2(x) exp2f(x)
#endif

typedef __attribute__((ext_vector_type(8))) short short8_t;
typedef __attribute__((ext_vector_type(4))) float f32x4;

__device__ __forceinline__ short f2bf(float f) {
    __bf16 h = (__bf16)f;
    return __builtin_bit_cast(short, h);
}

#define PADK 72   // bf16 row stride for MFMA staging tiles (144 B)

// Stage one e-group (4 e's) of lig[16 l] and rec[16 r] slices as bf16.
__device__ __forceinline__ void stage_group(const float* __restrict__ lig,
                                            const float* __restrict__ rec,
                                            int l0, int r0, int g,
                                            short* __restrict__ ligbuf,
                                            short* __restrict__ recbuf,
                                            int tid) {
#pragma unroll
    for (int i = 0; i < 4; ++i) {              // lig: 4e x 16l x 16 float4
        int idx = i * 256 + tid;
        int eg  = idx >> 8;
        int row = (idx >> 4) & 15;
        int f4  = idx & 15;
        float4 v = *(const float4*)(lig + ((size_t)(l0 + row) * 32 + (4 * g + eg)) * 64 + f4 * 4);
        short4 p;
        p.x = f2bf(v.x); p.y = f2bf(v.y); p.z = f2bf(v.z); p.w = f2bf(v.w);
        *(short4*)(&ligbuf[eg * (16 * PADK) + row * PADK + f4 * 4]) = p;
    }
#pragma unroll
    for (int i = 0; i < 4; ++i) {              // rec: 4e x 16r x 16 float4
        int idx = i * 256 + tid;
        int eg  = idx >> 8;
        int row = (idx >> 4) & 15;
        int f4  = idx & 15;
        float4 v = *(const float4*)(rec + ((size_t)(r0 + row) * 32 + (4 * g + eg)) * 64 + f4 * 4);
        short4 p;
        p.x = f2bf(v.x); p.y = f2bf(v.y); p.z = f2bf(v.z); p.w = f2bf(v.w);
        *(short4*)(&recbuf[eg * (16 * PADK) + row * PADK + f4 * 4]) = p;
    }
}

// ---------------------------------------------------------------------------
// Fused kernel: block = 16 l x 16 r x (only the needed e's).
// Phase 0: distances d[t] per (l,r) pair -> block-max e0 -> gmax (uniform).
// Phase 1: atn tile [e][16 l][16 r] (bf16) via MFMA into LDS, e-groups
//          0..gmax only (double-buffered staging; one e per wave per group).
// Phase 2: acc[t] += atn * exp2(-(d*SFAC - e*MUS)^2) over the 5-wide window
//          around e0 (window always within staged range); reduce -> partials.
// Grid 512 blocks (8 lt x 64 rt), 256 threads = 4 waves, 2 blocks/CU.
// ---------------------------------------------------------------------------
__global__ __launch_bounds__(256) void fused_kernel(const float* __restrict__ lig,
                                                    const float* __restrict__ rec,
                                                    const float* __restrict__ ligc,
                                                    const float* __restrict__ recc,
                                                    float* __restrict__ partials) {
    const int tid = threadIdx.x;
    const int lt  = blockIdx.x >> 6;     // 0..7
    const int rtc = blockIdx.x & 63;     // 0..63
    const int l0  = lt * 16;
    const int r0  = rtc * 16;

    __shared__ short atn_s[E_CNT * 16 * 16];                 // e*256 + l*16 + r, 16 KB
    __shared__ __align__(16) short lig_s[2][4 * 16 * PADK];  // 18432 B
    __shared__ __align__(16) short rec_s[2][4 * 16 * PADK];  // 18432 B
    __shared__ float ligc_s[T_CNT * 16 * 3];                 // [t][l][xyz], 3 KB
    __shared__ float red[4][T_CNT];
    __shared__ int gmax_s[4];

    // stage ligc tile: 768 floats
#pragma unroll
    for (int i = 0; i < 3; ++i) {
        int idx = i * 256 + tid;         // t*48 + (l*3+c)
        int t   = idx / 48;
        int rem = idx - t * 48;
        ligc_s[idx] = ligc[(size_t)t * 384 + l0 * 3 + rem];
    }

    const int wave = tid >> 6;
    const int lane = tid & 63;
    const int fr   = lane & 15;
    const int kg   = lane >> 4;

    // ---- Phase 0: distances + block-uniform gmax ----
    const int l_loc = tid >> 4;
    const int r_loc = tid & 15;
    const int r_g   = r0 + r_loc;

    const float rx = recc[r_g * 3 + 0];
    const float ry = recc[r_g * 3 + 1];
    const float rz = recc[r_g * 3 + 2];

    __syncthreads();                      // ligc_s ready

    float d[T_CNT];
    float e0max = 2.0f;
#pragma unroll
    for (int t = 0; t < T_CNT; ++t) {
        float dx = ligc_s[t * 48 + l_loc * 3 + 0] - rx;
        float dy = ligc_s[t * 48 + l_loc * 3 + 1] - ry;
        float dz = ligc_s[t * 48 + l_loc * 3 + 2] - rz;
        d[t] = sqrtf(dx * dx + dy * dy + dz * dz);
        float e0f = rintf(d[t] * SFAC * INV_MUS);
        e0max = fmaxf(e0max, fminf(e0f, 29.0f));
    }
    // wave max, then cross-wave max
#pragma unroll
    for (int m = 32; m >= 1; m >>= 1) e0max = fmaxf(e0max, __shfl_xor(e0max, m, 64));
    if (lane == 0) gmax_s[wave] = ((int)e0max + 2) >> 2;   // highest needed e-group
    __syncthreads();
    const int gmax = max(max(gmax_s[0], gmax_s[1]), max(gmax_s[2], gmax_s[3]));

    // ---- Phase 1: GEMM into LDS, e-groups 0..gmax, double-buffered ----
    stage_group(lig, rec, l0, r0, 0, lig_s[0], rec_s[0], tid);
    __syncthreads();

    for (int g = 0; g <= gmax; ++g) {
        if (g < gmax) stage_group(lig, rec, l0, r0, g + 1, lig_s[(g + 1) & 1], rec_s[(g + 1) & 1], tid);

        // compute e = 4g + wave from buffer g&1
        const short* A = &lig_s[g & 1][wave * (16 * PADK)];
        const short* B = &rec_s[g & 1][wave * (16 * PADK)];
        short8_t a0 = *(const short8_t*)(A + fr * PADK + kg * 8);
        short8_t a1 = *(const short8_t*)(A + fr * PADK + 32 + kg * 8);
        short8_t b0 = *(const short8_t*)(B + fr * PADK + kg * 8);
        short8_t b1 = *(const short8_t*)(B + fr * PADK + 32 + kg * 8);
        f32x4 c = (f32x4){0.f, 0.f, 0.f, 0.f};
        c = __builtin_amdgcn_mfma_f32_16x16x32_bf16(a0, b0, c, 0, 0, 0);
        c = __builtin_amdgcn_mfma_f32_16x16x32_bf16(a1, b1, c, 0, 0, 0);

        // C/D layout: col(r) = lane&15, row(l) = (lane>>4)*4 + j
        const int e    = 4 * g + wave;
        const int rowb = (lane >> 4) * 4;
#pragma unroll
        for (int j = 0; j < 4; ++j) {
            atn_s[e * 256 + (rowb + j) * 16 + fr] = f2bf(c[j]);
        }
        __syncthreads();
    }

    // ---- Phase 2: energy. 1 pair/thread (same l_loc/r_loc as phase 0) ----
    float acc[T_CNT];
#pragma unroll
    for (int t = 0; t < T_CNT; ++t) acc[t] = 0.0f;

    const int pbase = l_loc * 16 + r_loc;
#pragma unroll
    for (int t = 0; t < T_CNT; ++t) {
        const float u = d[t] * SFAC;
        float e0f = rintf(u * INV_MUS);
        e0f = fminf(fmaxf(e0f, 2.0f), 29.0f);   // window [e0-2, e0+2] in [0,31]
        const int   em2 = (int)e0f - 2;
        const float um  = fmaf(e0f, -MUS, u);
#pragma unroll
        for (int k = 0; k < 5; ++k) {
            const float w  = um - (float)(k - 2) * MUS;
            const float ae = __uint_as_float(
                (unsigned)(unsigned short)atn_s[(em2 + k) * 256 + pbase] << 16);
            acc[t] = fmaf(ae, EXP2(-(w * w)), acc[t]);
        }
    }

    // Block reduction: shuffle within wave, then LDS across 4 waves.
#pragma unroll
    for (int t = 0; t < T_CNT; ++t) {
#pragma unroll
        for (int m = 32; m >= 1; m >>= 1) acc[t] += __shfl_xor(acc[t], m, 64);
    }
    if (lane == 0) {
#pragma unroll
        for (int t = 0; t < T_CNT; ++t) red[wave][t] = acc[t];
    }
    __syncthreads();
    if (tid < T_CNT) {
        float s = red[0][tid] + red[1][tid] + red[2][tid] + red[3][tid];
        partials[(size_t)blockIdx.x * T_CNT + tid] = s;
    }
}

// ---------------------------------------------------------------------------
// Deterministic final reduce of 512 x 16 partials -> out[16]
// ---------------------------------------------------------------------------
__global__ __launch_bounds__(256) void final_reduce(const float* __restrict__ partials,
                                                    float* __restrict__ out) {
    __shared__ float red[16][17];
    const int t = threadIdx.x & 15;
    const int g = threadIdx.x >> 4;
    float s = 0.0f;
    for (int b = g; b < 512; b += 16) s += partials[(size_t)b * 16 + t];
    red[g][t] = s;
    __syncthreads();
    if (threadIdx.x < 16) {
        float v = 0.0f;
#pragma unroll
        for (int g2 = 0; g2 < 16; ++g2) v += red[g2][threadIdx.x];
        out[threadIdx.x] = v;
    }
}

extern "C" void kernel_launch(void* const* d_in, const int* in_sizes, int n_in,
                              void* d_out, int out_size, void* d_ws, size_t ws_size,
                              hipStream_t stream) {
    const float* lig  = (const float*)d_in[0];   // [128,32,64]
    const float* rec  = (const float*)d_in[1];   // [1024,32,64]
    const float* ligc = (const float*)d_in[2];   // [16,128,3]
    const float* recc = (const float*)d_in[3];   // [1024,3]
    float* out = (float*)d_out;                  // [16]

    float* partials = (float*)d_ws;              // 512*16 floats

    fused_kernel<<<512, 256, 0, stream>>>(lig, rec, ligc, recc, partials);
    final_reduce<<<1, 256, 0, stream>>>(partials, out);
}